// Round 2
// baseline (224.212 us; speedup 1.0000x reference)
//
#include <hip/hip_runtime.h>
#include <hip/hip_fp16.h>

#define TT    64        // output tokens per block
#define HALO  9         // (KERNEL_SIZE-1)*DILATION
#define NTOK  73        // TT + HALO
#define NROWS 80        // 5 MFMA m-tiles of 16
#define EPS   1.1920929e-07f

typedef __attribute__((ext_vector_type(8))) _Float16 f16x8;
typedef __attribute__((ext_vector_type(4))) float f32x4;

__device__ __forceinline__ float redsum16(float x) {
    // sum over the 16 lanes of a row; result in all 16 lanes
    x += __shfl_xor(x, 1, 16);
    x += __shfl_xor(x, 2, 16);
    x += __shfl_xor(x, 4, 16);
    x += __shfl_xor(x, 8, 16);
    return x;
}

extern "C" __global__ __launch_bounds__(320)
void engram_fused(const float* __restrict__ emb,   // [16,8192,32]
                  const float* __restrict__ hid,   // [16,8192,4,32]
                  const float* __restrict__ Wv,    // [32,32]
                  const float* __restrict__ bv,    // [32]
                  const float* __restrict__ Wk,    // [4,32,32]
                  const float* __restrict__ bk,    // [4,32]
                  const float* __restrict__ n1w,   // [4,32]
                  const float* __restrict__ n2w,   // [4,32]
                  const float* __restrict__ cnw,   // [4,32]
                  const float* __restrict__ cw,    // [128,1,4]
                  float* __restrict__ out)         // [16,8192,128]
{
    __shared__ __align__(16) __half s_emb[NROWS * 32];   // f16 emb rows (i -> t0-9+i)
    __shared__ __align__(16) __half s_w[160 * 32];       // rows: n<32 Wv[n], else Wk[n-32]
    __shared__ __align__(16) __half s_xn[NTOK * 128];    // x_norm handoff
    __shared__ __align__(16) float  s_val[TT * 32];      // value for output tokens
    __shared__ float  s_gate[TT * 4];                    // gate for output tokens

    const int tid  = threadIdx.x;
    const int b    = blockIdx.x >> 7;      // 16 batches
    const int tile = blockIdx.x & 127;     // 128 tiles of 64 tokens
    const int t0   = tile * TT;

    // ---- stage emb tile (f16), rows i=0..79 ~ t=t0-9+i, zero outside [0,8192) ----
    for (int e = tid; e < NROWS * 32; e += 320) {
        int i = e >> 5, d = e & 31;
        int t = t0 - HALO + i;
        float v = 0.f;
        if (t >= 0 && t < 8192) v = emb[((b << 13) + t) * 32 + d];
        s_emb[e] = __float2half(v);
    }
    // ---- stage projection weights (f16) ----
    for (int e = tid; e < 160 * 32; e += 320) {
        int n = e >> 5, d = e & 31;
        float v = (n < 32) ? Wv[n * 32 + d] : Wk[(n - 32) * 32 + d];
        s_w[e] = __float2half(v);
    }
    __syncthreads();

    // ---- per-wave MFMA: D[token 16][n 160] for mtile = wave id ----
    const int wv  = tid >> 6;     // 0..4
    const int ln  = tid & 63;
    const int l15 = ln & 15;
    const int q   = ln >> 4;      // quad 0..3

    f32x4 D[10];
    {
        // A frag: A[m=l15][k=q*8+j] = emb row (wv*16+l15), d = q*8..q*8+7
        f16x8 a = *(const f16x8*)&s_emb[(wv * 16 + l15) * 32 + q * 8];
        #pragma unroll
        for (int nt = 0; nt < 10; ++nt) {
            int n = nt * 16 + l15;
            float bias = (n < 32) ? bv[n] : bk[n - 32];
            f32x4 c = {bias, bias, bias, bias};
            // B frag: B[k=q*8+j][n=l15] = weight row n, d = q*8..q*8+7
            f16x8 bf = *(const f16x8*)&s_w[n * 32 + q * 8];
            D[nt] = __builtin_amdgcn_mfma_f32_16x16x32_f16(a, bf, c, 0, 0, 0);
        }
    }

    // per-lane norm weights for its two column groups (c = h*16 + l15)
    float pn1[4][2], pn2[4][2], pcn[4][2];
    #pragma unroll
    for (int g = 0; g < 4; ++g) {
        #pragma unroll
        for (int h = 0; h < 2; ++h) {
            int c = h * 16 + l15;
            pn1[g][h] = n1w[g * 32 + c];
            pn2[g][h] = n2w[g * 32 + c];
            pcn[g][h] = cnw[g * 32 + c];
        }
    }

    // ---- load Q (hidden_states) matching the D register layout ----
    const int ibase = wv * 16 + q * 4;   // token row = ibase + r
    float Q[4][2][4];
    #pragma unroll
    for (int r = 0; r < 4; ++r) {
        int t = t0 - HALO + ibase + r;
        bool ok = (t >= 0 && t < 8192);
        #pragma unroll
        for (int g = 0; g < 4; ++g) {
            #pragma unroll
            for (int h = 0; h < 2; ++h) {
                float v = 0.f;
                if (ok) v = hid[(((b << 13) + t) * 4 + g) * 32 + h * 16 + l15];
                Q[g][h][r] = v;
            }
        }
    }

    // ---- norms + gate + x_norm, all in registers, row-of-16 reductions ----
    #pragma unroll
    for (int r = 0; r < 4; ++r) {
        const int i = ibase + r;                 // 0..79
        const float V0 = D[0][r], V1 = D[1][r];
        float msv = redsum16(V0 * V0 + V1 * V1) * (1.f / 32.f);
        float gs[4];
        float xn[4][2];
        #pragma unroll
        for (int g = 0; g < 4; ++g) {
            float K0 = D[2 + g * 2 + 0][r], K1 = D[2 + g * 2 + 1][r];
            float msk = redsum16(K0 * K0 + K1 * K1) * (1.f / 32.f);
            float rk = rsqrtf(msk + EPS);
            float q0 = Q[g][0][r], q1 = Q[g][1][r];
            float msq = redsum16(q0 * q0 + q1 * q1) * (1.f / 32.f);
            float rq = rsqrtf(msq + EPS);
            float nk0 = K0 * rk * pn1[g][0], nk1 = K1 * rk * pn1[g][1];
            float nq0 = q0 * rq * pn2[g][0], nq1 = q1 * rq * pn2[g][1];
            float dot = redsum16(nk0 * nq0 + nk1 * nq1) * 0.17677669529663689f; // /sqrt(32)
            float sa = sqrtf(fmaxf(fabsf(dot), 1e-6f));
            float gate = 1.f / (1.f + __expf(-copysignf(sa, dot)));
            gs[g] = gate;
            float inv = rsqrtf(gate * gate * msv + EPS);
            float sc = gate * inv;
            xn[g][0] = sc * V0 * pcn[g][0];
            xn[g][1] = sc * V1 * pcn[g][1];
        }
        if (i < NTOK) {
            // causal padding: conv input is literally ZERO for t<0 (reference
            // pads x_bct with zeros). Bias+RMSNorm would otherwise fabricate
            // O(1) values out of zero emb rows.
            const float tval = (t0 - HALO + i >= 0) ? 1.f : 0.f;
            #pragma unroll
            for (int g = 0; g < 4; ++g) {
                s_xn[i * 128 + g * 32 + 0  + l15] = __float2half(tval * xn[g][0]);
                s_xn[i * 128 + g * 32 + 16 + l15] = __float2half(tval * xn[g][1]);
            }
            if (i >= HALO) {
                int j = i - HALO;
                s_val[j * 32 + 0  + l15] = V0;
                s_val[j * 32 + 16 + l15] = V1;
                if (l15 < 4) {
                    float gsel = (l15 == 0) ? gs[0] : (l15 == 1) ? gs[1]
                               : (l15 == 2) ? gs[2] : gs[3];
                    s_gate[j * 4 + l15] = gsel;
                }
            }
        }
    }
    __syncthreads();

    // ---- phase 2: causal dilated depthwise conv + SiLU + residual add ----
    const float4* cw4p = (const float4*)cw;
    for (int idx = tid; idx < TT * 128; idx += 320) {
        int j = idx >> 7, ch = idx & 127;
        float4 w4 = cw4p[ch];
        float x0 = __half2float(s_xn[(j + 0) * 128 + ch]);
        float x1 = __half2float(s_xn[(j + 3) * 128 + ch]);
        float x2 = __half2float(s_xn[(j + 6) * 128 + ch]);
        float x3 = __half2float(s_xn[(j + 9) * 128 + ch]);
        float y = x0 * w4.x + x1 * w4.y + x2 * w4.z + x3 * w4.w;
        float sy = y / (1.f + __expf(-y));
        float gated = s_gate[j * 4 + (ch >> 5)] * s_val[j * 32 + (ch & 31)];
        out[((b << 13) + t0 + j) * 128 + ch] = gated + sy;
    }
}

extern "C" void kernel_launch(void* const* d_in, const int* in_sizes, int n_in,
                              void* d_out, int out_size, void* d_ws, size_t ws_size,
                              hipStream_t stream) {
    const float* emb = (const float*)d_in[0];
    const float* hid = (const float*)d_in[1];
    const float* Wv  = (const float*)d_in[2];
    const float* bvp = (const float*)d_in[3];
    const float* Wk  = (const float*)d_in[4];
    const float* bkp = (const float*)d_in[5];
    const float* n1  = (const float*)d_in[6];
    const float* n2  = (const float*)d_in[7];
    const float* cn  = (const float*)d_in[8];
    const float* cw  = (const float*)d_in[9];
    float* out = (float*)d_out;

    dim3 grid(16 * 128);   // b * (8192/64)
    dim3 block(320);       // 5 waves = 5 MFMA m-tiles
    engram_fused<<<grid, block, 0, stream>>>(emb, hid, Wv, bvp, Wk, bkp, n1, n2, cn, cw, out);
}